// Round 5
// baseline (594.386 us; speedup 1.0000x reference)
//
#include <hip/hip_runtime.h>
#include <hip/hip_bf16.h>

// QuantizedLinear: out[M,N] = inp[M,K] @ (qw[N,K] * scale[N])^T
// M = 4096, K = 4096, N = 12288.
// Pass 1: convert A fp32->bf16, W int32->bf16 into d_ws.
// Pass 2: 256x256 8-wave bf16 GEMM, 4 phases/K-tile with READ-AHEAD-1:
//   phase p issues ds_reads for phase p+1, MFMA(p) runs on frags from p-1,
//   compiler emits counted lgkmcnt -> LDS drain overlaps MFMA (fix for the
//   measured 35% lockstep). T1 XCD swizzle, T2 both-sides XOR swizzle,
//   T4 counted vmcnt(2) (per-wave, placed before a barrier for collective
//   safety), T5 setprio. global_load_lds w=16.

#define K_DIM 4096
#define N_DIM 12288

constexpr int BM = 256;
constexpr int BN = 256;
constexpr int BK = 64;
constexpr int NT = K_DIM / BK;   // 64

typedef float  f32x4  __attribute__((ext_vector_type(4)));
typedef int    i32x4  __attribute__((ext_vector_type(4)));
typedef short  bf16x8 __attribute__((ext_vector_type(8)));
typedef unsigned short u16x8 __attribute__((ext_vector_type(8)));
typedef unsigned short u16x4 __attribute__((ext_vector_type(4)));

__device__ __forceinline__ unsigned short f32_to_bf16(float f) {
    unsigned int u = __builtin_bit_cast(unsigned int, f);
    u += 0x7FFFu + ((u >> 16) & 1u);   // round-to-nearest-even
    return (unsigned short)(u >> 16);
}

// ---------------- Pass 1: conversion kernels ----------------

__global__ __launch_bounds__(256)
void cvt_a_kernel(const float* __restrict__ A, unsigned short* __restrict__ Ab, int n8) {
    int stride = gridDim.x * blockDim.x;
    for (int i = blockIdx.x * blockDim.x + threadIdx.x; i < n8; i += stride) {
        const f32x4 a0 = *(const f32x4*)(A + (size_t)i * 8);
        const f32x4 a1 = *(const f32x4*)(A + (size_t)i * 8 + 4);
        u16x8 h;
        h[0] = f32_to_bf16(a0[0]); h[1] = f32_to_bf16(a0[1]);
        h[2] = f32_to_bf16(a0[2]); h[3] = f32_to_bf16(a0[3]);
        h[4] = f32_to_bf16(a1[0]); h[5] = f32_to_bf16(a1[1]);
        h[6] = f32_to_bf16(a1[2]); h[7] = f32_to_bf16(a1[3]);
        *(u16x8*)(Ab + (size_t)i * 8) = h;
    }
}

__global__ __launch_bounds__(256)
void cvt_w_kernel(const int* __restrict__ W, unsigned short* __restrict__ Wb, int n8) {
    int stride = gridDim.x * blockDim.x;
    for (int i = blockIdx.x * blockDim.x + threadIdx.x; i < n8; i += stride) {
        const i32x4 w0 = *(const i32x4*)(W + (size_t)i * 8);
        const i32x4 w1 = *(const i32x4*)(W + (size_t)i * 8 + 4);
        u16x8 h;  // int8 values are exact in bf16
        h[0] = f32_to_bf16((float)w0[0]); h[1] = f32_to_bf16((float)w0[1]);
        h[2] = f32_to_bf16((float)w0[2]); h[3] = f32_to_bf16((float)w0[3]);
        h[4] = f32_to_bf16((float)w1[0]); h[5] = f32_to_bf16((float)w1[1]);
        h[6] = f32_to_bf16((float)w1[2]); h[7] = f32_to_bf16((float)w1[3]);
        *(u16x8*)(Wb + (size_t)i * 8) = h;
    }
}

// ---------------- Pass 2: 256^2 read-ahead bf16 GEMM ----------------

__device__ __forceinline__ void gload_lds16(const void* g, void* l) {
    __builtin_amdgcn_global_load_lds(
        (const __attribute__((address_space(1))) unsigned int*)g,
        (__attribute__((address_space(3))) unsigned int*)l,
        16, 0, 0);
}

__global__ __launch_bounds__(512, 2)
void gemm_bf16_256(const unsigned short* __restrict__ Ab,  // [M,K] bf16
                   const unsigned short* __restrict__ Wb,  // [N,K] bf16
                   const float* __restrict__ Sw,           // [N]
                   float* __restrict__ Out,                // [M,N]
                   int M) {
    __shared__ __align__(16) unsigned short As[2][BM * BK];   // 2 x 32 KB
    __shared__ __align__(16) unsigned short Bs[2][BN * BK];   // 2 x 32 KB

    const int tid  = threadIdx.x;
    const int lane = tid & 63;
    const int wid  = tid >> 6;          // 0..7
    const int wm   = wid >> 2;          // 0..1  (128-row half)
    const int wn   = wid & 3;           // 0..3  (64-col strip)

    // T1: XCD swizzle (768 blocks, 96/XCD), column-major in chunk -> W-panel L2 reuse
    const int nwgy = M / BM;                 // 16
    const int nwg  = (N_DIM / BN) * nwgy;    // 768
    const int cpx  = nwg >> 3;               // 96
    const int bid  = blockIdx.x;
    const int swz  = (bid & 7) * cpx + (bid >> 3);
    const int bx   = swz / nwgy;
    const int by   = swz % nwgy;
    const int bm   = by * BM;
    const int bn   = bx * BN;

    // staging: chunk c = j*8+wid -> LDS c*1024B + lane*16B; T2 pre-swizzled global col
    const int srow = wid * 8 + (lane >> 3);
    const int scol = ((lane & 7) ^ (lane >> 3)) * 8;

    #define STG_H(G, grow0, k0, L)                                                  \
        do {                                                                        \
            gload_lds16((G) + (size_t)((grow0) + srow) * K_DIM + (k0) + scol,       \
                        (L) + wid * 512);                                           \
            gload_lds16((G) + (size_t)((grow0) + 64 + srow) * K_DIM + (k0) + scol,  \
                        (L) + (8 + wid) * 512);                                     \
        } while (0)

    f32x4 acc[8][4];
    #pragma unroll
    for (int i = 0; i < 8; ++i)
        #pragma unroll
        for (int j = 0; j < 4; ++j)
            acc[i][j] = (f32x4){0.f, 0.f, 0.f, 0.f};

    const int c0  = lane & 15;
    const int kg  = (lane >> 4) * 8;
    const int rsw = (c0 & 7) * 8;       // read-side swizzle (row&7 == c0&7)

    bf16x8 af[8][2];      // current tile's 8 m-frags x 2 k-slices
    bf16x8 bf0[2][2];     // qn=0 frags
    bf16x8 bf1[2][2];     // qn=1 frags

    #define RD_A(base, src, row0)                                                    \
        _Pragma("unroll") for (int mf = 0; mf < 4; ++mf)                            \
        _Pragma("unroll") for (int ks = 0; ks < 2; ++ks)                            \
            af[(base) + mf][ks] = *(const bf16x8*)&(src)[((row0) + mf * 16) * 64 + ((ks * 32 + kg) ^ rsw)];

    #define RD_B(dst, src, row0)                                                    \
        _Pragma("unroll") for (int nf = 0; nf < 2; ++nf)                            \
        _Pragma("unroll") for (int ks = 0; ks < 2; ++ks)                            \
            (dst)[nf][ks] = *(const bf16x8*)&(src)[((row0) + nf * 16) * 64 + ((ks * 32 + kg) ^ rsw)];

    #define CLUSTER(qm, qn, BF)                                                     \
        __builtin_amdgcn_s_setprio(1);                                             \
        _Pragma("unroll") for (int ks = 0; ks < 2; ++ks)                            \
        _Pragma("unroll") for (int mf = 0; mf < 4; ++mf)                            \
        _Pragma("unroll") for (int nf = 0; nf < 2; ++nf)                            \
            acc[(qm)*4 + mf][(qn)*2 + nf] = __builtin_amdgcn_mfma_f32_16x16x32_bf16( \
                af[(qm)*4 + mf][ks], (BF)[nf][ks], acc[(qm)*4 + mf][(qn)*2 + nf],    \
                0, 0, 0);                                                            \
        __builtin_amdgcn_s_setprio(0);

    // ---- prologue: stage tile0 (A,B) + A(1); collective landing; t0 frag reads ----
    STG_H(Ab, bm,       0,  &As[0][0]);
    STG_H(Ab, bm + 128, 0,  &As[0][8192]);
    STG_H(Wb, bn,       0,  &Bs[0][0]);
    STG_H(Wb, bn + 128, 0,  &Bs[0][8192]);
    STG_H(Ab, bm,       BK, &As[1][0]);
    STG_H(Ab, bm + 128, BK, &As[1][8192]);
    asm volatile("s_waitcnt vmcnt(4)" ::: "memory");   // tile0 landed; A(1) in flight
    __builtin_amdgcn_s_barrier();

    {
        const unsigned short* A0f = &As[0][(wm * 128 + c0) * 64];
        const unsigned short* B0f = &Bs[0][(wn * 64 + c0) * 64];
        RD_A(0, A0f, 0);        // af0-3(t0)
        RD_B(bf0, B0f, 0);      // bf0(t0)
    }

    for (int t = 0; t < NT; ++t) {
        const int cur = t & 1;
        const unsigned short* Ac = &As[cur][(wm * 128 + c0) * 64];
        const unsigned short* Bc = &Bs[cur][(wn * 64 + c0) * 64];
        const unsigned short* An = &As[cur ^ 1][(wm * 128 + c0) * 64];
        const unsigned short* Bn = &Bs[cur ^ 1][(wn * 64 + c0) * 64];
        unsigned short* Bdst = &Bs[cur ^ 1][0];   // B(t+1)
        unsigned short* Adst = &As[cur][0];       // A(t+2)
        const int k1 = (t + 1) * BK;
        const int k2 = (t + 2) * BK;

        // ---- ph0: MFMA(0,0)[af0-3,bf0]; read bf1(t); post: STG B0(t+1) ----
        RD_B(bf1, Bc, 32);
        __builtin_amdgcn_sched_barrier(0);
        CLUSTER(0, 0, bf0);
        __builtin_amdgcn_sched_barrier(0);        // STG must not hoist above cluster
        if (t + 1 < NT) STG_H(Wb, bn, k1, Bdst);  // safe: bf0 reads retired pre-cluster
        __builtin_amdgcn_s_barrier();

        // ---- ph1: MFMA(0,1)[af0-3,bf1]; read af4-7(t); top: STG B1(t+1) ----
        if (t + 1 < NT) STG_H(Wb, bn + 128, k1, Bdst + 8192);
        RD_A(4, Ac, 64);
        __builtin_amdgcn_sched_barrier(0);
        CLUSTER(0, 1, bf1);
        __builtin_amdgcn_s_barrier();

        // ---- ph2: MFMA(1,0)[af4-7,bf0]; post: STG A0(t+2); counted vmcnt pre-barrier ----
        CLUSTER(1, 0, bf0);
        __builtin_amdgcn_sched_barrier(0);        // STG after af4-7 retire
        if (t + 2 < NT) STG_H(Ab, bm, k2, Adst);
        if (t < NT - 2) {
            asm volatile("s_waitcnt vmcnt(2)" ::: "memory");  // A(t+1),B(t+1) landed; A0(t+2) in flight
        } else {
            asm volatile("s_waitcnt vmcnt(0)" ::: "memory");
        }
        __builtin_amdgcn_s_barrier();             // collective: next-tile reads now safe

        // ---- ph3: MFMA(1,1)[af4-7,bf1]; STG A1(t+2); read af0-3(t+1), bf0(t+1) ----
        if (t + 2 < NT) STG_H(Ab, bm + 128, k2, Adst + 8192);
        if (t + 1 < NT) {
            RD_A(0, An, 0);
            RD_B(bf0, Bn, 0);
        }
        __builtin_amdgcn_sched_barrier(0);
        CLUSTER(1, 1, bf1);
        __builtin_amdgcn_s_barrier();
    }
    #undef CLUSTER
    #undef RD_A
    #undef RD_B
    #undef STG_H

    // ---- epilogue: C/D col = lane&15 (B row), row = (lane>>4)*4 + j (A row) ----
    const int r0 = (lane >> 4) * 4;
    #pragma unroll
    for (int n = 0; n < 4; ++n) {
        const int col = bn + wn * 64 + n * 16 + c0;
        const float s = Sw[col];
        #pragma unroll
        for (int m = 0; m < 8; ++m) {
            const int rowb = bm + wm * 128 + m * 16 + r0;
            #pragma unroll
            for (int j = 0; j < 4; ++j)
                Out[(size_t)(rowb + j) * N_DIM + col] = acc[m][n][j] * s;
        }
    }
}

// ---------------- Fallback (fused, if ws too small) ----------------

constexpr int FBM = 128, FBN = 128, FBK = 64, FPAD = 8;

__global__ __launch_bounds__(256)
void qlinear_fused_kernel(const float* __restrict__ A, const int* __restrict__ Wq,
                          const float* __restrict__ Sw, float* __restrict__ Out, int M) {
    __shared__ unsigned short Asf[FBM][FBK + FPAD];
    __shared__ unsigned short Bsf[FBN][FBK + FPAD];
    const int tid  = threadIdx.x;
    const int lane = tid & 63;
    const int wid  = tid >> 6;
    const int wm   = wid >> 1;
    const int wn   = wid & 1;
    const int bm = blockIdx.y * FBM;
    const int bn = blockIdx.x * FBN;
    const int rowT = tid >> 4;
    const int kq   = tid & 15;
    f32x4 acc[4][4];
    #pragma unroll
    for (int i = 0; i < 4; ++i)
        #pragma unroll
        for (int j = 0; j < 4; ++j) acc[i][j] = (f32x4){0.f,0.f,0.f,0.f};
    const int c0 = lane & 15;
    const int kg = (lane >> 4) * 8;
    for (int k0 = 0; k0 < K_DIM; k0 += FBK) {
        #pragma unroll
        for (int it = 0; it < 8; ++it) {
            const int r = it * 16 + rowT;
            const f32x4 a4 = *(const f32x4*)(A + (size_t)(bm + r) * K_DIM + k0 + kq * 4);
            u16x4 h;
            h[0]=f32_to_bf16(a4[0]); h[1]=f32_to_bf16(a4[1]);
            h[2]=f32_to_bf16(a4[2]); h[3]=f32_to_bf16(a4[3]);
            *(u16x4*)&Asf[r][kq*4] = h;
        }
        #pragma unroll
        for (int it = 0; it < 8; ++it) {
            const int r = it * 16 + rowT;
            const i32x4 w4 = *(const i32x4*)(Wq + (size_t)(bn + r) * K_DIM + k0 + kq * 4);
            u16x4 h;
            h[0]=f32_to_bf16((float)w4[0]); h[1]=f32_to_bf16((float)w4[1]);
            h[2]=f32_to_bf16((float)w4[2]); h[3]=f32_to_bf16((float)w4[3]);
            *(u16x4*)&Bsf[r][kq*4] = h;
        }
        __syncthreads();
        #pragma unroll
        for (int ks = 0; ks < 2; ++ks) {
            const int kk = ks * 32 + kg;
            bf16x8 af2[4], bfr[4];
            #pragma unroll
            for (int mf = 0; mf < 4; ++mf)
                af2[mf] = *(const bf16x8*)&Asf[wm*64 + mf*16 + c0][kk];
            #pragma unroll
            for (int nf = 0; nf < 4; ++nf)
                bfr[nf] = *(const bf16x8*)&Bsf[wn*64 + nf*16 + c0][kk];
            #pragma unroll
            for (int mf = 0; mf < 4; ++mf)
                #pragma unroll
                for (int nf = 0; nf < 4; ++nf)
                    acc[mf][nf] = __builtin_amdgcn_mfma_f32_16x16x32_bf16(
                        af2[mf], bfr[nf], acc[mf][nf], 0, 0, 0);
        }
        __syncthreads();
    }
    const int r0 = (lane >> 4) * 4;
    #pragma unroll
    for (int nf = 0; nf < 4; ++nf) {
        const int col = bn + wn*64 + nf*16 + c0;
        const float s = Sw[col];
        #pragma unroll
        for (int mf = 0; mf < 4; ++mf) {
            const int rowb = bm + wm*64 + mf*16 + r0;
            #pragma unroll
            for (int j = 0; j < 4; ++j)
                Out[(size_t)(rowb + j) * N_DIM + col] = acc[mf][nf][j] * s;
        }
    }
}

extern "C" void kernel_launch(void* const* d_in, const int* in_sizes, int n_in,
                              void* d_out, int out_size, void* d_ws, size_t ws_size,
                              hipStream_t stream) {
    const float* inp = (const float*)d_in[0];
    const int*   qw  = (const int*)d_in[1];
    const float* sw  = (const float*)d_in[2];
    float*       out = (float*)d_out;

    const int M = in_sizes[0] / K_DIM;                         // 4096
    const size_t nA = (size_t)M * K_DIM;
    const size_t nW = (size_t)N_DIM * K_DIM;
    const size_t need = (nA + nW) * sizeof(unsigned short);    // 128 MiB

    if (ws_size >= need && (M % BM) == 0) {
        unsigned short* Abf = (unsigned short*)d_ws;
        unsigned short* Wbf = Abf + nA;
        cvt_a_kernel<<<2048, 256, 0, stream>>>(inp, Abf, (int)(nA / 8));
        cvt_w_kernel<<<2048, 256, 0, stream>>>(qw, Wbf, (int)(nW / 8));
        dim3 grid((N_DIM / BN) * (M / BM));                    // 768
        gemm_bf16_256<<<grid, 512, 0, stream>>>(Abf, Wbf, sw, out, M);
    } else {
        dim3 grid(N_DIM / FBN, M / FBM);
        qlinear_fused_kernel<<<grid, 256, 0, stream>>>(inp, qw, sw, out, M);
    }
}